// Round 1
// baseline (1156.649 us; speedup 1.0000x reference)
//
#include <hip/hip_runtime.h>
#include <hip/hip_bf16.h>
#include <cstdint>
#include <cstddef>

#define B_ 2
#define T_ 1024
#define D_ 2048
#define H_ 16
#define DK_ 128
#define DV_ 128
#define ROWS (B_*T_)      // 2048
#define NCAT 10240        // 5*2048 concatenated projection outputs
#define YSTRIDE 10240

typedef __attribute__((ext_vector_type(8))) short bf16x8;
typedef __attribute__((ext_vector_type(4))) float f32x4;

__device__ inline unsigned short f2bf(float f){
    union { float f; unsigned int u; } v; v.f = f;
    unsigned int r = (v.u + 0x7fffu + ((v.u >> 16) & 1u)) >> 16;
    return (unsigned short)r;
}
__device__ inline float sigm(float x){ return 1.0f / (1.0f + __expf(-x)); }

// ---------------- fp32 -> bf16 cast (RNE) ----------------
__global__ void cast_bf16_kernel(const float* __restrict__ src,
                                 unsigned short* __restrict__ dst, int n){
    int i = (blockIdx.x * blockDim.x + threadIdx.x) * 4;
    if (i >= n) return;
    float4 f = *(const float4*)(src + i);
    ushort4 u;
    u.x = f2bf(f.x); u.y = f2bf(f.y); u.z = f2bf(f.z); u.w = f2bf(f.w);
    *(ushort4*)(dst + i) = u;
}

// ---------------- bf16 GEMM: C[M,N] = A[M,K] * Bm[N,K]^T, fp32 out ----------------
// 128x128 tile, 4 waves (2x2), each wave 64x64 via 4x4 mfma_f32_16x16x32_bf16.
// epilogue: n >= act_start -> sigmoid(y + (n < bias_end ? bias[n-act_start] : 0))
__global__ __launch_bounds__(256) void gemm_bt(
    const unsigned short* __restrict__ A,
    const unsigned short* __restrict__ Bm,
    float* __restrict__ C, int M, int N, int K,
    int act_start, const float* __restrict__ bias, int bias_end)
{
    __shared__ __align__(16) unsigned short lA[128*40];  // +8 pad breaks bank conflicts
    __shared__ __align__(16) unsigned short lB[128*40];
    const int tid  = threadIdx.x;
    const int wave = tid >> 6, lane = tid & 63;
    const int quad = lane >> 4, l16 = lane & 15;
    const int wm = wave >> 1, wn = wave & 1;
    const int m0 = blockIdx.y * 128, n0 = blockIdx.x * 128;

    f32x4 acc[4][4];
    #pragma unroll
    for (int i = 0; i < 4; i++)
        #pragma unroll
        for (int j = 0; j < 4; j++) acc[i][j] = (f32x4){0.f,0.f,0.f,0.f};

    for (int k0 = 0; k0 < K; k0 += 32) {
        __syncthreads();
        #pragma unroll
        for (int s = 0; s < 2; s++) {
            int ch = tid + s*256;            // 512 chunks of 8 bf16 (16B)
            int r = ch >> 2, c8 = (ch & 3) * 8;
            *(uint4*)(&lA[r*40 + c8]) = *(const uint4*)(A  + (size_t)(m0 + r)*K + k0 + c8);
            *(uint4*)(&lB[r*40 + c8]) = *(const uint4*)(Bm + (size_t)(n0 + r)*K + k0 + c8);
        }
        __syncthreads();
        bf16x8 af[4], bfr[4];
        #pragma unroll
        for (int i = 0; i < 4; i++) {
            af[i]  = *(const bf16x8*)(&lA[(wm*64 + i*16 + l16)*40 + quad*8]);
            bfr[i] = *(const bf16x8*)(&lB[(wn*64 + i*16 + l16)*40 + quad*8]);
        }
        #pragma unroll
        for (int i = 0; i < 4; i++)
            #pragma unroll
            for (int j = 0; j < 4; j++)
                acc[i][j] = __builtin_amdgcn_mfma_f32_16x16x32_bf16(af[i], bfr[j], acc[i][j], 0, 0, 0);
    }

    #pragma unroll
    for (int i = 0; i < 4; i++) {
        int m = m0 + wm*64 + i*16 + quad*4;        // C/D: row = quad*4 + reg
        #pragma unroll
        for (int j = 0; j < 4; j++) {
            int n = n0 + wn*64 + j*16 + l16;       // C/D: col = lane&15
            #pragma unroll
            for (int r = 0; r < 4; r++) {
                float y = acc[i][j][r];
                if (n >= act_start) {
                    float bsum = (n < bias_end) ? bias[n - act_start] : 0.0f;
                    y = sigm(y + bsum);
                }
                C[(size_t)(m + r)*N + n] = y;
            }
        }
    }
}

// ---------------- beta = sigmoid(x @ Wb^T + bb), fp32 exact ----------------
__global__ __launch_bounds__(256) void beta_kernel(const float* __restrict__ x,
        const float* __restrict__ Wb, const float* __restrict__ bb,
        float* __restrict__ beta)
{
    __shared__ float xs[2048];
    int row = blockIdx.x;
    const float* xr = x + (size_t)row * 2048;
    for (int i = threadIdx.x; i < 2048; i += 256) xs[i] = xr[i];
    __syncthreads();
    int wave = threadIdx.x >> 6, lane = threadIdx.x & 63;
    for (int hh = 0; hh < 4; hh++) {
        int h = wave*4 + hh;
        const float* w = Wb + (size_t)h * 2048;
        float s = 0.f;
        for (int i = lane; i < 2048; i += 64) s = fmaf(xs[i], w[i], s);
        for (int m = 1; m < 64; m <<= 1) s += __shfl_xor(s, m);
        if (lane == 0) beta[row*16 + h] = sigm(s + bb[h]);
    }
}

// ---------------- causal depthwise conv (K=4) + silu + scale ----------------
// in: Y[B, T, YSTRIDE] at col_off; out: [B, T, 2048]
__global__ void conv_silu_kernel(const float* __restrict__ Y, int col_off,
                                 const float* __restrict__ cw, const float* __restrict__ cb,
                                 float scale, float* __restrict__ out)
{
    int gid = blockIdx.x * blockDim.x + threadIdx.x;  // 32768 total
    int c = gid & 2047;
    int tmp = gid >> 11;
    int tch = tmp & 7;
    int b = tmp >> 3;
    int t0 = tch * 128;
    const float w0 = cw[c*4+0], w1 = cw[c*4+1], w2 = cw[c*4+2], w3 = cw[c*4+3];
    const float bias = cb[c];
    const float* src = Y + (size_t)b*T_*YSTRIDE + col_off + c;
    float* dst = out + (size_t)b*T_*2048 + c;
    float y0 = (t0 >= 3) ? src[(size_t)(t0-3)*YSTRIDE] : 0.f;
    float y1 = (t0 >= 2) ? src[(size_t)(t0-2)*YSTRIDE] : 0.f;
    float y2 = (t0 >= 1) ? src[(size_t)(t0-1)*YSTRIDE] : 0.f;
    for (int t = t0; t < t0 + 128; t++) {
        float y3 = src[(size_t)t*YSTRIDE];
        float s = fmaf(w0,y0, fmaf(w1,y1, fmaf(w2,y2, fmaf(w3,y3, bias))));
        float r = s * (1.0f/(1.0f + __expf(-s))) * scale;
        dst[(size_t)t*2048] = r;
        y0 = y1; y1 = y2; y2 = y3;
    }
}

// ---------------- gated delta recurrence ----------------
// rows of S independent: wave = 2 rows x 32 lanes x 4 k-elems. 512 blocks x 256 thr.
__global__ __launch_bounds__(256) void recurrence_kernel(
    const float* __restrict__ q, const float* __restrict__ k, const float* __restrict__ v,
    const float* __restrict__ a, int a_stride,
    const float* __restrict__ beta, float* __restrict__ o)
{
    int blk = blockIdx.x;             // (b*16+h)*16 + chunk
    int chunk = blk & 15;
    int bh = blk >> 4;
    int h = bh & 15, b = bh >> 4;
    int wave = threadIdx.x >> 6, lane = threadIdx.x & 63;
    int vrow = chunk*8 + wave*2 + (lane >> 5);   // 0..127
    int lr = lane & 31;
    size_t rbase = (size_t)b * T_;
    const float* kp = k + rbase*2048 + h*128 + lr*4;
    const float* qp = q + rbase*2048 + h*128 + lr*4;
    const float* vp = v + rbase*2048 + h*128 + vrow;
    const float* ap = a + rbase*(size_t)a_stride + h*128 + vrow;
    const float* bp = beta + rbase*16 + h;
    float*       op = o + rbase*2048 + h*128 + vrow;

    float4 s = {0.f,0.f,0.f,0.f};
    for (int t = 0; t < T_; t++) {
        float4 kv = *(const float4*)kp;
        float4 qv = *(const float4*)qp;
        float vt = *vp, at = *ap, bt = *bp;
        // Sk = S_{t-1} @ k_t (pre-decay, per reference)
        float sk = fmaf(s.x,kv.x, fmaf(s.y,kv.y, fmaf(s.z,kv.z, s.w*kv.w)));
        sk += __shfl_xor(sk, 1); sk += __shfl_xor(sk, 2); sk += __shfl_xor(sk, 4);
        sk += __shfl_xor(sk, 8); sk += __shfl_xor(sk, 16);
        float c = bt * (sk - vt);
        s.x = fmaf(at, s.x, -c*kv.x);
        s.y = fmaf(at, s.y, -c*kv.y);
        s.z = fmaf(at, s.z, -c*kv.z);
        s.w = fmaf(at, s.w, -c*kv.w);
        float ov = fmaf(s.x,qv.x, fmaf(s.y,qv.y, fmaf(s.z,qv.z, s.w*qv.w)));
        ov += __shfl_xor(ov, 1); ov += __shfl_xor(ov, 2); ov += __shfl_xor(ov, 4);
        ov += __shfl_xor(ov, 8); ov += __shfl_xor(ov, 16);
        if (lr == 0) *op = ov;
        kp += 2048; qp += 2048; vp += 2048; ap += a_stride; bp += 16; op += 2048;
    }
}

// ---------------- LayerNorm over DV, * gate, -> bf16 ----------------
__global__ __launch_bounds__(256) void ln_gate_kernel(
    const float* __restrict__ o, const float* __restrict__ g, int g_stride,
    const float* __restrict__ ln_g, const float* __restrict__ ln_b,
    unsigned short* __restrict__ og)
{
    int wave = threadIdx.x >> 6, lane = threadIdx.x & 63;
    int gidx = blockIdx.x*4 + wave;     // 0..32767
    int row = gidx >> 4, h = gidx & 15;
    const float* ob = o + (size_t)row*2048 + h*128;
    int d0 = lane*2;
    float2 xv = *(const float2*)(ob + d0);
    float s = xv.x + xv.y, ss = xv.x*xv.x + xv.y*xv.y;
    for (int m = 1; m < 64; m <<= 1) { s += __shfl_xor(s, m); ss += __shfl_xor(ss, m); }
    float mu  = s * (1.f/128.f);
    float var = ss * (1.f/128.f) - mu*mu;
    float inv = rsqrtf(var + 1e-5f);
    const float* gb = g + (size_t)row*g_stride + h*128;
    float r0 = ((xv.x - mu)*inv*ln_g[d0]   + ln_b[d0])   * gb[d0];
    float r1 = ((xv.y - mu)*inv*ln_g[d0+1] + ln_b[d0+1]) * gb[d0+1];
    ushort2 u; u.x = f2bf(r0); u.y = f2bf(r1);
    *(ushort2*)(og + (size_t)row*2048 + h*128 + d0) = u;
}

extern "C" void kernel_launch(void* const* d_in, const int* in_sizes, int n_in,
                              void* d_out, int out_size, void* d_ws, size_t ws_size,
                              hipStream_t stream)
{
    const float* x   = (const float*)d_in[0];
    const float* Wq  = (const float*)d_in[1];
    const float* Wk  = (const float*)d_in[2];
    const float* Wv  = (const float*)d_in[3];
    const float* Wa  = (const float*)d_in[4];
    const float* ba  = (const float*)d_in[5];
    const float* Wb  = (const float*)d_in[6];
    const float* bb  = (const float*)d_in[7];
    const float* cqw = (const float*)d_in[8];
    const float* cqb = (const float*)d_in[9];
    const float* ckw = (const float*)d_in[10];
    const float* ckb = (const float*)d_in[11];
    const float* cvw = (const float*)d_in[12];
    const float* cvb = (const float*)d_in[13];
    const float* Wg  = (const float*)d_in[14];
    const float* lng = (const float*)d_in[15];
    const float* lnb = (const float*)d_in[16];
    const float* Wo  = (const float*)d_in[17];
    float* out = (float*)d_out;

    char* ws = (char*)d_ws;
    size_t off = 0;
    auto alloc = [&](size_t bytes){ void* p = ws + off; off += (bytes + 255) & ~(size_t)255; return p; };
    unsigned short* xb   = (unsigned short*)alloc((size_t)ROWS*D_*2);
    unsigned short* Wcat = (unsigned short*)alloc((size_t)NCAT*D_*2);
    unsigned short* Wob  = (unsigned short*)alloc((size_t)D_*D_*2);
    float* Y    = (float*)alloc((size_t)ROWS*YSTRIDE*4);  // [q|k|v|a|g] pre-act / act
    float* qs   = (float*)alloc((size_t)ROWS*2048*4);
    float* ks   = (float*)alloc((size_t)ROWS*2048*4);
    float* vs   = (float*)alloc((size_t)ROWS*2048*4);
    float* betb = (float*)alloc((size_t)ROWS*16*4);
    float* ov   = (float*)alloc((size_t)ROWS*2048*4);
    unsigned short* og = (unsigned short*)alloc((size_t)ROWS*2048*2);
    (void)ws_size;

    const int n = ROWS * D_;          // 4M elems
    const int cg = n / 4 / 256;       // 4096 blocks
    size_t wsz = (size_t)D_ * D_;
    cast_bf16_kernel<<<cg, 256, 0, stream>>>(x,  xb, n);
    cast_bf16_kernel<<<cg, 256, 0, stream>>>(Wq, Wcat + 0*wsz, n);
    cast_bf16_kernel<<<cg, 256, 0, stream>>>(Wk, Wcat + 1*wsz, n);
    cast_bf16_kernel<<<cg, 256, 0, stream>>>(Wv, Wcat + 2*wsz, n);
    cast_bf16_kernel<<<cg, 256, 0, stream>>>(Wa, Wcat + 3*wsz, n);
    cast_bf16_kernel<<<cg, 256, 0, stream>>>(Wg, Wcat + 4*wsz, n);
    cast_bf16_kernel<<<cg, 256, 0, stream>>>(Wo, Wob, n);

    // fused projections: [2048,10240] = xb @ Wcat^T ; sigmoid on a (with bias ba) and g
    gemm_bt<<<dim3(80,16), 256, 0, stream>>>(xb, Wcat, Y, ROWS, NCAT, D_, 6144, ba, 8192);

    beta_kernel<<<2048, 256, 0, stream>>>(x, Wb, bb, betb);

    const float kscale = 0.08838834764831845f;  // DK^-0.5
    conv_silu_kernel<<<128, 256, 0, stream>>>(Y, 0,    cqw, cqb, 1.0f,   qs);
    conv_silu_kernel<<<128, 256, 0, stream>>>(Y, 2048, ckw, ckb, kscale, ks);
    conv_silu_kernel<<<128, 256, 0, stream>>>(Y, 4096, cvw, cvb, 1.0f,   vs);

    recurrence_kernel<<<512, 256, 0, stream>>>(qs, ks, vs, Y + 6144, YSTRIDE, betb, ov);

    ln_gate_kernel<<<8192, 256, 0, stream>>>(ov, Y + 8192, YSTRIDE, lng, lnb, og);

    // out = og @ Wo^T
    gemm_bt<<<dim3(16,16), 256, 0, stream>>>(og, Wob, out, ROWS, D_, D_, 1<<30, nullptr, 0);
}

// Round 2
// 849.127 us; speedup vs baseline: 1.3622x; 1.3622x over previous
//
#include <hip/hip_runtime.h>
#include <hip/hip_bf16.h>
#include <cstdint>
#include <cstddef>

#define B_ 2
#define T_ 1024
#define D_ 2048
#define H_ 16
#define DK_ 128
#define DV_ 128
#define ROWS (B_*T_)      // 2048
// Y columns: [q 0:2048 | k 2048:4096 | v 4096:6144 | a 6144:8192 | g 8192:10240 | beta 10240:10256 | pad :10368]
#define NCAT 10368
#define YSTRIDE 10368

typedef __attribute__((ext_vector_type(8))) short bf16x8;
typedef __attribute__((ext_vector_type(4))) float f32x4;

__device__ inline unsigned short f2bf(float f){
    union { float f; unsigned int u; } v; v.f = f;
    unsigned int r = (v.u + 0x7fffu + ((v.u >> 16) & 1u)) >> 16;
    return (unsigned short)r;
}
__device__ inline float sigm(float x){ return 1.0f / (1.0f + __expf(-x)); }

// ---- DPP helpers: sum over each 32-lane group, result lands in lane 31/63 ----
template<int CTRL>
__device__ __forceinline__ float dpp_add(float x){
    int t = __builtin_amdgcn_update_dpp(0, __builtin_bit_cast(int, x), CTRL, 0xf, 0xf, true);
    return x + __builtin_bit_cast(float, t);
}
__device__ __forceinline__ float grp32_sum31(float x){
    x = dpp_add<0x111>(x);   // row_shr:1
    x = dpp_add<0x112>(x);   // row_shr:2
    x = dpp_add<0x114>(x);   // row_shr:4
    x = dpp_add<0x118>(x);   // row_shr:8  -> lane15/31/47/63 hold 16-lane sums
    x = dpp_add<0x142>(x);   // row_bcast15 -> lane31/63 hold 32-lane sums
    return x;
}
__device__ __forceinline__ float bcast31f(float x){
    // all lanes read lane 31 of their 32-group (bit-mode swizzle: and=0, or=31)
    return __builtin_bit_cast(float, __builtin_amdgcn_ds_swizzle(__builtin_bit_cast(int, x), 0x03E0));
}

// ---------------- fused fp32 -> bf16 casts (one launch) ----------------
struct Cast8 { const float* p[8]; };  // x, Wq, Wk, Wv, Wa, Wg, Wo, Wb
__global__ void cast_all_kernel(Cast8 args, unsigned short* __restrict__ xb,
                                unsigned short* __restrict__ Wcat,
                                unsigned short* __restrict__ Wob){
    int blk = blockIdx.x;
    if (blk >= 28704) {  // zero-pad rows 10256..10367 of Wcat
        int i = (blk - 28704)*1024 + threadIdx.x*4;
        *(ushort4*)(Wcat + (size_t)10256*2048 + i) = (ushort4){0,0,0,0};
        return;
    }
    const float* src; unsigned short* dst; int i;
    if (blk >= 28672) {  // Wb -> Wcat rows 10240..10255
        i = (blk - 28672)*1024 + threadIdx.x*4;
        src = args.p[7]; dst = Wcat + (size_t)10240*2048;
    } else {
        int seg = blk >> 12;
        i = (blk & 4095)*1024 + threadIdx.x*4;
        src = args.p[seg];
        if (seg == 0)      dst = xb;
        else if (seg <= 5) dst = Wcat + (size_t)(seg-1)*4194304;
        else               dst = Wob;
    }
    float4 f = *(const float4*)(src + i);
    ushort4 u; u.x = f2bf(f.x); u.y = f2bf(f.y); u.z = f2bf(f.z); u.w = f2bf(f.w);
    *(ushort4*)(dst + i) = u;
}

// ---------------- bf16 GEMM: C[M,N] = A[M,K] * Bm[N,K]^T, fp32 out ----------------
// epilogue (act_start=6144 path): n in [6144,8192): sigmoid(y+ba); [8192,10240): sigmoid(y);
// [10240,10256): sigmoid(y+bb) = beta
__global__ __launch_bounds__(256) void gemm_bt(
    const unsigned short* __restrict__ A,
    const unsigned short* __restrict__ Bm,
    float* __restrict__ C, int M, int N, int K,
    int act_start, const float* __restrict__ ba, const float* __restrict__ bbeta)
{
    __shared__ __align__(16) unsigned short lA[128*40];
    __shared__ __align__(16) unsigned short lB[128*40];
    const int tid  = threadIdx.x;
    const int wave = tid >> 6, lane = tid & 63;
    const int quad = lane >> 4, l16 = lane & 15;
    const int wm = wave >> 1, wn = wave & 1;
    const int m0 = blockIdx.y * 128, n0 = blockIdx.x * 128;

    f32x4 acc[4][4];
    #pragma unroll
    for (int i = 0; i < 4; i++)
        #pragma unroll
        for (int j = 0; j < 4; j++) acc[i][j] = (f32x4){0.f,0.f,0.f,0.f};

    for (int k0 = 0; k0 < K; k0 += 32) {
        __syncthreads();
        #pragma unroll
        for (int s = 0; s < 2; s++) {
            int ch = tid + s*256;
            int r = ch >> 2, c8 = (ch & 3) * 8;
            *(uint4*)(&lA[r*40 + c8]) = *(const uint4*)(A  + (size_t)(m0 + r)*K + k0 + c8);
            *(uint4*)(&lB[r*40 + c8]) = *(const uint4*)(Bm + (size_t)(n0 + r)*K + k0 + c8);
        }
        __syncthreads();
        bf16x8 af[4], bfr[4];
        #pragma unroll
        for (int i = 0; i < 4; i++) {
            af[i]  = *(const bf16x8*)(&lA[(wm*64 + i*16 + l16)*40 + quad*8]);
            bfr[i] = *(const bf16x8*)(&lB[(wn*64 + i*16 + l16)*40 + quad*8]);
        }
        #pragma unroll
        for (int i = 0; i < 4; i++)
            #pragma unroll
            for (int j = 0; j < 4; j++)
                acc[i][j] = __builtin_amdgcn_mfma_f32_16x16x32_bf16(af[i], bfr[j], acc[i][j], 0, 0, 0);
    }

    #pragma unroll
    for (int i = 0; i < 4; i++) {
        int m = m0 + wm*64 + i*16 + quad*4;
        #pragma unroll
        for (int j = 0; j < 4; j++) {
            int n = n0 + wn*64 + j*16 + l16;
            #pragma unroll
            for (int r = 0; r < 4; r++) {
                float y = acc[i][j][r];
                if (n >= act_start) {
                    float bsum = 0.0f;
                    if (n < 8192) bsum = ba[n - 6144];
                    else if (n >= 10240 && n < 10256) bsum = bbeta[n - 10240];
                    y = sigm(y + bsum);
                }
                C[(size_t)(m + r)*N + n] = y;
            }
        }
    }
}

// ---------------- causal depthwise conv (K=4) + silu + scale ----------------
__global__ void conv_silu_kernel(const float* __restrict__ Y, int col_off,
                                 const float* __restrict__ cw, const float* __restrict__ cb,
                                 float scale, float* __restrict__ out)
{
    int gid = blockIdx.x * blockDim.x + threadIdx.x;  // 32768 total
    int c = gid & 2047;
    int tmp = gid >> 11;
    int tch = tmp & 7;
    int b = tmp >> 3;
    int t0 = tch * 128;
    const float w0 = cw[c*4+0], w1 = cw[c*4+1], w2 = cw[c*4+2], w3 = cw[c*4+3];
    const float bias = cb[c];
    const float* src = Y + (size_t)b*T_*YSTRIDE + col_off + c;
    float* dst = out + (size_t)b*T_*2048 + c;
    float y0 = (t0 >= 3) ? src[(size_t)(t0-3)*YSTRIDE] : 0.f;
    float y1 = (t0 >= 2) ? src[(size_t)(t0-2)*YSTRIDE] : 0.f;
    float y2 = (t0 >= 1) ? src[(size_t)(t0-1)*YSTRIDE] : 0.f;
    for (int t = t0; t < t0 + 128; t++) {
        float y3 = src[(size_t)t*YSTRIDE];
        float s = fmaf(w0,y0, fmaf(w1,y1, fmaf(w2,y2, fmaf(w3,y3, bias))));
        float r = s * (1.0f/(1.0f + __expf(-s))) * scale;
        dst[(size_t)t*2048] = r;
        y0 = y1; y1 = y2; y2 = y3;
    }
}

// ---------------- gated delta recurrence (DPP reduce + depth-2 prefetch) ----------------
// wave = 2 v-rows x 32 lanes x 4 k-elems; 512 blocks x 256 thr = 2048 waves
__global__ __launch_bounds__(256) void recurrence_kernel(
    const float* __restrict__ q, const float* __restrict__ k, const float* __restrict__ v,
    const float* __restrict__ a, const float* __restrict__ beta, float* __restrict__ o)
{
    const int blk = blockIdx.x;           // (b*16+h)*16 + chunk
    const int chunk = blk & 15;
    const int bh = blk >> 4;
    const int h = bh & 15, b = bh >> 4;
    const int lane = threadIdx.x & 63;
    const int wave = threadIdx.x >> 6;
    const int vrow = chunk*8 + wave*2 + (lane >> 5);
    const int lr = lane & 31;
    const size_t rbase = (size_t)b * T_;
    const float4* kp = (const float4*)(k + rbase*2048 + (size_t)h*128) + lr;
    const float4* qp = (const float4*)(q + rbase*2048 + (size_t)h*128) + lr;
    const float*  vp = v + rbase*2048 + h*128 + vrow;
    const float*  ap = a + rbase*YSTRIDE + h*128 + vrow;     // a = Y+6144, stride YSTRIDE
    const float*  bp = beta + rbase*YSTRIDE + h;             // beta = Y+10240, stride YSTRIDE
    float*        op = o + rbase*2048 + h*128 + vrow;

    float4 s = {0.f,0.f,0.f,0.f};

#define RSTEP(kv, qv, vt, at, bt, oidx) { \
    float sk = fmaf(s.x,(kv).x, fmaf(s.y,(kv).y, fmaf(s.z,(kv).z, s.w*(kv).w))); \
    sk = bcast31f(grp32_sum31(sk)); \
    float c = (bt) * (sk - (vt)); \
    s.x = fmaf((at), s.x, -c*(kv).x); \
    s.y = fmaf((at), s.y, -c*(kv).y); \
    s.z = fmaf((at), s.z, -c*(kv).z); \
    s.w = fmaf((at), s.w, -c*(kv).w); \
    float ov_ = fmaf(s.x,(qv).x, fmaf(s.y,(qv).y, fmaf(s.z,(qv).z, s.w*(qv).w))); \
    ov_ = grp32_sum31(ov_); \
    if (lr == 31) op[(size_t)(oidx)*2048] = ov_; \
}

    // prime pipeline: steps 0 and 1 loaded
    float4 kA = kp[0],   qA = qp[0];
    float  vA = vp[0],   aA = ap[0],        bA = bp[0];
    float4 kB = kp[512], qB = qp[512];
    float  vB = vp[2048], aB = ap[YSTRIDE], bB = bp[YSTRIDE];

    #pragma unroll 1
    for (int t = 0; t < T_; t += 2) {
        // prefetch t+2, t+3 (last iter reads a couple rows past end -- stays inside d_ws, values unused)
        float4 kN0 = kp[(t+2)*512], qN0 = qp[(t+2)*512];
        float  vN0 = vp[(size_t)(t+2)*2048], aN0 = ap[(size_t)(t+2)*YSTRIDE], bN0 = bp[(size_t)(t+2)*YSTRIDE];
        float4 kN1 = kp[(t+3)*512], qN1 = qp[(t+3)*512];
        float  vN1 = vp[(size_t)(t+3)*2048], aN1 = ap[(size_t)(t+3)*YSTRIDE], bN1 = bp[(size_t)(t+3)*YSTRIDE];

        RSTEP(kA, qA, vA, aA, bA, t);
        RSTEP(kB, qB, vB, aB, bB, t+1);

        kA = kN0; qA = qN0; vA = vN0; aA = aN0; bA = bN0;
        kB = kN1; qB = qN1; vB = vN1; aB = aN1; bB = bN1;
    }
#undef RSTEP
}

// ---------------- LayerNorm over DV, * gate, -> bf16 ----------------
__global__ __launch_bounds__(256) void ln_gate_kernel(
    const float* __restrict__ o, const float* __restrict__ g, int g_stride,
    const float* __restrict__ ln_g, const float* __restrict__ ln_b,
    unsigned short* __restrict__ og)
{
    int wave = threadIdx.x >> 6, lane = threadIdx.x & 63;
    int gidx = blockIdx.x*4 + wave;     // 0..32767
    int row = gidx >> 4, h = gidx & 15;
    const float* ob = o + (size_t)row*2048 + h*128;
    int d0 = lane*2;
    float2 xv = *(const float2*)(ob + d0);
    float s = xv.x + xv.y, ss = xv.x*xv.x + xv.y*xv.y;
    for (int m = 1; m < 64; m <<= 1) { s += __shfl_xor(s, m); ss += __shfl_xor(ss, m); }
    float mu  = s * (1.f/128.f);
    float var = ss * (1.f/128.f) - mu*mu;
    float inv = rsqrtf(var + 1e-5f);
    const float* gb = g + (size_t)row*g_stride + h*128;
    float r0 = ((xv.x - mu)*inv*ln_g[d0]   + ln_b[d0])   * gb[d0];
    float r1 = ((xv.y - mu)*inv*ln_g[d0+1] + ln_b[d0+1]) * gb[d0+1];
    ushort2 u; u.x = f2bf(r0); u.y = f2bf(r1);
    *(ushort2*)(og + (size_t)row*2048 + h*128 + d0) = u;
}

extern "C" void kernel_launch(void* const* d_in, const int* in_sizes, int n_in,
                              void* d_out, int out_size, void* d_ws, size_t ws_size,
                              hipStream_t stream)
{
    const float* x   = (const float*)d_in[0];
    const float* Wq  = (const float*)d_in[1];
    const float* Wk  = (const float*)d_in[2];
    const float* Wv  = (const float*)d_in[3];
    const float* Wa  = (const float*)d_in[4];
    const float* ba  = (const float*)d_in[5];
    const float* Wb  = (const float*)d_in[6];
    const float* bb  = (const float*)d_in[7];
    const float* cqw = (const float*)d_in[8];
    const float* cqb = (const float*)d_in[9];
    const float* ckw = (const float*)d_in[10];
    const float* ckb = (const float*)d_in[11];
    const float* cvw = (const float*)d_in[12];
    const float* cvb = (const float*)d_in[13];
    const float* Wg  = (const float*)d_in[14];
    const float* lng = (const float*)d_in[15];
    const float* lnb = (const float*)d_in[16];
    const float* Wo  = (const float*)d_in[17];
    float* out = (float*)d_out;

    char* ws = (char*)d_ws;
    size_t off = 0;
    auto alloc = [&](size_t bytes){ void* p = ws + off; off += (bytes + 255) & ~(size_t)255; return p; };
    unsigned short* xb   = (unsigned short*)alloc((size_t)ROWS*D_*2);       // also reused as og
    unsigned short* Wcat = (unsigned short*)alloc((size_t)NCAT*D_*2);
    unsigned short* Wob  = (unsigned short*)alloc((size_t)D_*D_*2);
    float* Y  = (float*)alloc((size_t)ROWS*YSTRIDE*4);
    float* qs = (float*)alloc((size_t)ROWS*2048*4);
    float* ks = (float*)alloc((size_t)ROWS*2048*4);
    float* vs = (float*)alloc((size_t)ROWS*2048*4);
    float* ov = (float*)alloc((size_t)ROWS*2048*4);
    unsigned short* og = xb;   // xb dead after projection GEMM; reuse for ln output
    (void)ws_size;

    Cast8 cargs;
    cargs.p[0]=x; cargs.p[1]=Wq; cargs.p[2]=Wk; cargs.p[3]=Wv; cargs.p[4]=Wa;
    cargs.p[5]=Wg; cargs.p[6]=Wo; cargs.p[7]=Wb;
    cast_all_kernel<<<28928, 256, 0, stream>>>(cargs, xb, Wcat, Wob);

    // fused projections + beta: [2048,10368] = xb @ Wcat^T
    gemm_bt<<<dim3(81,16), 256, 0, stream>>>(xb, Wcat, Y, ROWS, NCAT, D_, 6144, ba, bb);

    const float kscale = 0.08838834764831845f;  // DK^-0.5
    conv_silu_kernel<<<128, 256, 0, stream>>>(Y, 0,    cqw, cqb, 1.0f,   qs);
    conv_silu_kernel<<<128, 256, 0, stream>>>(Y, 2048, ckw, ckb, kscale, ks);
    conv_silu_kernel<<<128, 256, 0, stream>>>(Y, 4096, cvw, cvb, 1.0f,   vs);

    recurrence_kernel<<<512, 256, 0, stream>>>(qs, ks, vs, Y + 6144, Y + 10240, ov);

    ln_gate_kernel<<<8192, 256, 0, stream>>>(ov, Y + 8192, YSTRIDE, lng, lnb, og);

    gemm_bt<<<dim3(16,16), 256, 0, stream>>>(og, Wob, out, ROWS, D_, D_, 1<<30, nullptr, nullptr);
}